// Round 1
// baseline (22.475 us; speedup 1.0000x reference)
//
#include <hip/hip_runtime.h>

#define NTHREADS 1024

constexpr int HID    = 20;
constexpr int NEXP   = 16;
// floats per expert in LDS. 1348*4B = 5392B (16B aligned); 1348/4=337 odd ->
// expert bases spread over 8 distinct 4-bank groups -> <=2-way LDS aliasing (free).
constexpr int ESTRIDE = 1348;

constexpr int OFF_W1 = 0;     // [2][20]
constexpr int OFF_B1 = 40;    // [20]
constexpr int OFF_W2 = 60;    // [20][20]
constexpr int OFF_B2 = 460;
constexpr int OFF_W3 = 480;
constexpr int OFF_B3 = 880;
constexpr int OFF_W4 = 900;
constexpr int OFF_B4 = 1300;
constexpr int OFF_W5 = 1320;  // [20]
constexpr int OFF_B5 = 1340;  // [1]

__device__ __forceinline__ float silu(float v) {
    // v * sigmoid(v); raw v_rcp is ~2^-22 rel err, far inside the 4.7e-2 abs threshold
    float e = __expf(-v);
    return v * __builtin_amdgcn_rcpf(1.0f + e);
}

// region index per reference _region_mask: first cell lower bound inclusive,
// upper bounds inclusive, outside [-4,4] (or NaN) -> -1 (=> output 0)
__device__ __forceinline__ int cell_idx(float v) {
    if (!(v >= -4.0f))  return -1;   // also catches NaN
    if (v <= -0.674f)   return 0;
    if (v <= 0.0f)      return 1;
    if (v <= 0.674f)    return 2;
    if (v <= 4.0f)      return 3;
    return -1;
}

template<int PER_E>
__device__ __forceinline__ void stage(float* smem, const float* __restrict__ src,
                                      int off, int tid) {
    constexpr int TOTAL = NEXP * PER_E;
    for (int i = tid; i < TOTAL; i += NTHREADS) {
        int e = i / PER_E;          // compile-time constant divisor -> magic mul
        int k = i - e * PER_E;
        smem[e * ESTRIDE + off + k] = src[i];
    }
}

// one 20->20 layer + silu, weights row-major [h_in][k_out] in LDS
__device__ __forceinline__ void layer20(float (&h)[HID],
                                        const float* __restrict__ Wm,
                                        const float* __restrict__ bv) {
    float acc[HID];
    const float4* bb = reinterpret_cast<const float4*>(bv);
    #pragma unroll
    for (int q = 0; q < 5; ++q) {
        float4 b = bb[q];
        acc[4*q+0] = b.x; acc[4*q+1] = b.y; acc[4*q+2] = b.z; acc[4*q+3] = b.w;
    }
    #pragma unroll
    for (int k = 0; k < HID; ++k) {
        const float hk = h[k];
        const float4* row = reinterpret_cast<const float4*>(Wm + k * HID); // 80B stride, 16B aligned
        #pragma unroll
        for (int q = 0; q < 5; ++q) {
            float4 w = row[q];
            acc[4*q+0] = fmaf(hk, w.x, acc[4*q+0]);
            acc[4*q+1] = fmaf(hk, w.y, acc[4*q+1]);
            acc[4*q+2] = fmaf(hk, w.z, acc[4*q+2]);
            acc[4*q+3] = fmaf(hk, w.w, acc[4*q+3]);
        }
    }
    #pragma unroll
    for (int j = 0; j < HID; ++j) h[j] = silu(acc[j]);
}

__global__ __launch_bounds__(NTHREADS, 4) void NetEval_2207613190845_kernel(
    const float* __restrict__ x,
    const float* __restrict__ W1, const float* __restrict__ b1,
    const float* __restrict__ W2, const float* __restrict__ b2,
    const float* __restrict__ W3, const float* __restrict__ b3,
    const float* __restrict__ W4, const float* __restrict__ b4,
    const float* __restrict__ W5, const float* __restrict__ b5,
    float* __restrict__ out, int n_total)
{
    __shared__ float smem[NEXP * ESTRIDE];   // 86,272 B -> 1 block/CU, 16 waves/CU
    const int tid = threadIdx.x;

    stage<40 >(smem, W1, OFF_W1, tid);
    stage<20 >(smem, b1, OFF_B1, tid);
    stage<400>(smem, W2, OFF_W2, tid);
    stage<20 >(smem, b2, OFF_B2, tid);
    stage<400>(smem, W3, OFF_W3, tid);
    stage<20 >(smem, b3, OFF_B3, tid);
    stage<400>(smem, W4, OFF_W4, tid);
    stage<20 >(smem, b4, OFF_B4, tid);
    stage<20 >(smem, W5, OFF_W5, tid);
    stage<1  >(smem, b5, OFF_B5, tid);
    __syncthreads();

    const int n = blockIdx.x * NTHREADS + tid;
    if (n >= n_total) return;

    const float2 xv = reinterpret_cast<const float2*>(x)[n];  // coalesced 8B/lane
    const int c = cell_idx(xv.x);
    const int r = cell_idx(xv.y);

    float result = 0.0f;
    if ((c | r) >= 0) {                  // both cells valid
        const float* W = &smem[(c * 4 + r) * ESTRIDE];

        float h[HID];
        // layer 1: 2 -> 20
        {
            const float4* w0 = reinterpret_cast<const float4*>(W + OFF_W1);
            const float4* w1 = reinterpret_cast<const float4*>(W + OFF_W1 + HID);
            const float4* bb = reinterpret_cast<const float4*>(W + OFF_B1);
            #pragma unroll
            for (int q = 0; q < 5; ++q) {
                float4 a0 = w0[q], a1 = w1[q], b = bb[q];
                h[4*q+0] = silu(fmaf(xv.x, a0.x, fmaf(xv.y, a1.x, b.x)));
                h[4*q+1] = silu(fmaf(xv.x, a0.y, fmaf(xv.y, a1.y, b.y)));
                h[4*q+2] = silu(fmaf(xv.x, a0.z, fmaf(xv.y, a1.z, b.z)));
                h[4*q+3] = silu(fmaf(xv.x, a0.w, fmaf(xv.y, a1.w, b.w)));
            }
        }
        // layers 2..4: 20 -> 20
        layer20(h, W + OFF_W2, W + OFF_B2);
        layer20(h, W + OFF_W3, W + OFF_B3);
        layer20(h, W + OFF_W4, W + OFF_B4);
        // layer 5: 20 -> 1
        float acc = W[OFF_B5];
        {
            const float4* w5 = reinterpret_cast<const float4*>(W + OFF_W5);
            #pragma unroll
            for (int q = 0; q < 5; ++q) {
                float4 w = w5[q];
                acc = fmaf(h[4*q+0], w.x, acc);
                acc = fmaf(h[4*q+1], w.y, acc);
                acc = fmaf(h[4*q+2], w.z, acc);
                acc = fmaf(h[4*q+3], w.w, acc);
            }
        }
        result = acc;
    }
    out[n] = result;   // coalesced 4B/lane
}

extern "C" void kernel_launch(void* const* d_in, const int* in_sizes, int n_in,
                              void* d_out, int out_size, void* d_ws, size_t ws_size,
                              hipStream_t stream) {
    const float* x  = (const float*)d_in[0];
    const float* W1 = (const float*)d_in[1];
    const float* b1 = (const float*)d_in[2];
    const float* W2 = (const float*)d_in[3];
    const float* b2 = (const float*)d_in[4];
    const float* W3 = (const float*)d_in[5];
    const float* b3 = (const float*)d_in[6];
    const float* W4 = (const float*)d_in[7];
    const float* b4 = (const float*)d_in[8];
    const float* W5 = (const float*)d_in[9];
    const float* b5 = (const float*)d_in[10];
    float* out = (float*)d_out;

    const int n_total = in_sizes[0] / 2;                 // 262144 samples
    const int grid = (n_total + NTHREADS - 1) / NTHREADS; // 256 blocks

    hipLaunchKernelGGL(NetEval_2207613190845_kernel, dim3(grid), dim3(NTHREADS), 0, stream,
                       x, W1, b1, W2, b2, W3, b3, W4, b4, W5, b5, out, n_total);
}

// Round 2
// 22.327 us; speedup vs baseline: 1.0066x; 1.0066x over previous
//
#include <hip/hip_runtime.h>

#define NTHREADS 1024

constexpr int HID    = 20;
constexpr int NEXP   = 16;
constexpr int NW     = NTHREADS / 64;  // 16 waves
constexpr int NB     = 17;             // 16 experts + 1 invalid bucket
// floats per expert in LDS. 1348*4B = 5392B (16B aligned).
constexpr int ESTRIDE = 1348;

constexpr int OFF_W1 = 0;     // [2][20]
constexpr int OFF_B1 = 40;    // [20]
constexpr int OFF_W2 = 60;    // [20][20]
constexpr int OFF_B2 = 460;
constexpr int OFF_W3 = 480;
constexpr int OFF_B3 = 880;
constexpr int OFF_W4 = 900;
constexpr int OFF_B4 = 1300;
constexpr int OFF_W5 = 1320;  // [20]
constexpr int OFF_B5 = 1340;  // [1]

__device__ __forceinline__ float silu(float v) {
    float e = __expf(-v);
    return v * __builtin_amdgcn_rcpf(1.0f + e);
}

// region index per reference _region_mask: first cell lower bound inclusive,
// upper bounds inclusive, outside [-4,4] (or NaN) -> -1 (=> output 0)
__device__ __forceinline__ int cell_idx(float v) {
    if (!(v >= -4.0f))  return -1;   // also catches NaN
    if (v <= -0.674f)   return 0;
    if (v <= 0.0f)      return 1;
    if (v <= 0.674f)    return 2;
    if (v <= 4.0f)      return 3;
    return -1;
}

// float4 staging: PER_E4 = float4-elements per expert; offsets all 16B-aligned
template<int PER_E4>
__device__ __forceinline__ void stage4(float* smem, const float* __restrict__ src,
                                       int off, int tid) {
    constexpr int TOTAL = NEXP * PER_E4;
    const float4* s4 = reinterpret_cast<const float4*>(src);
    for (int i = tid; i < TOTAL; i += NTHREADS) {
        int e = i / PER_E4;                 // const divisor -> magic mul
        int k = i - e * PER_E4;
        *reinterpret_cast<float4*>(&smem[e * ESTRIDE + off + 4 * k]) = s4[i];
    }
}

template<int PER_E>
__device__ __forceinline__ void stage1(float* smem, const float* __restrict__ src,
                                       int off, int tid) {
    constexpr int TOTAL = NEXP * PER_E;
    for (int i = tid; i < TOTAL; i += NTHREADS) {
        int e = i / PER_E;
        int k = i - e * PER_E;
        smem[e * ESTRIDE + off + k] = src[i];
    }
}

// one 20->20 layer + silu, weights row-major [h_in][k_out] in LDS
__device__ __forceinline__ void layer20(float (&h)[HID],
                                        const float* __restrict__ Wm,
                                        const float* __restrict__ bv) {
    float acc[HID];
    const float4* bb = reinterpret_cast<const float4*>(bv);
    #pragma unroll
    for (int q = 0; q < 5; ++q) {
        float4 b = bb[q];
        acc[4*q+0] = b.x; acc[4*q+1] = b.y; acc[4*q+2] = b.z; acc[4*q+3] = b.w;
    }
    #pragma unroll
    for (int k = 0; k < HID; ++k) {
        const float hk = h[k];
        const float4* row = reinterpret_cast<const float4*>(Wm + k * HID);
        #pragma unroll
        for (int q = 0; q < 5; ++q) {
            float4 w = row[q];
            acc[4*q+0] = fmaf(hk, w.x, acc[4*q+0]);
            acc[4*q+1] = fmaf(hk, w.y, acc[4*q+1]);
            acc[4*q+2] = fmaf(hk, w.z, acc[4*q+2]);
            acc[4*q+3] = fmaf(hk, w.w, acc[4*q+3]);
        }
    }
    #pragma unroll
    for (int j = 0; j < HID; ++j) h[j] = silu(acc[j]);
}

__global__ __launch_bounds__(NTHREADS, 4) void NetEval_2207613190845_kernel(
    const float* __restrict__ x,
    const float* __restrict__ W1, const float* __restrict__ b1,
    const float* __restrict__ W2, const float* __restrict__ b2,
    const float* __restrict__ W3, const float* __restrict__ b3,
    const float* __restrict__ W4, const float* __restrict__ b4,
    const float* __restrict__ W5, const float* __restrict__ b5,
    float* __restrict__ out, int n_total)
{
    __shared__ float  smem[NEXP * ESTRIDE];   // 86,272 B
    __shared__ float2 sx[NTHREADS];           //  8,192 B
    __shared__ int    sinfo[NTHREADS];        //  4,096 B  (orig tid | e<<12)
    __shared__ int    wavecnt[NW * NB];
    __shared__ int    waveoff[NW * NB];
    __shared__ int    tot[NB];
    __shared__ int    ebase[NB];

    const int tid = threadIdx.x;

    // ---- stage all 16 experts' weights (float4 where aligned) ----
    stage4<10 >(smem, W1, OFF_W1, tid);
    stage4<5  >(smem, b1, OFF_B1, tid);
    stage4<100>(smem, W2, OFF_W2, tid);
    stage4<5  >(smem, b2, OFF_B2, tid);
    stage4<100>(smem, W3, OFF_W3, tid);
    stage4<5  >(smem, b3, OFF_B3, tid);
    stage4<100>(smem, W4, OFF_W4, tid);
    stage4<5  >(smem, b4, OFF_B4, tid);
    stage4<5  >(smem, W5, OFF_W5, tid);
    stage1<1  >(smem, b5, OFF_B5, tid);

    // ---- load sample, compute expert bucket ----
    const int n  = blockIdx.x * NTHREADS + tid;
    const int nc = n < n_total ? n : (n_total - 1);
    const float2 xv = reinterpret_cast<const float2*>(x)[nc];   // coalesced 8B/lane
    const int c = cell_idx(xv.x);
    const int r = cell_idx(xv.y);
    const int e = (n < n_total && (c | r) >= 0) ? (c * 4 + r) : 16;

    // ---- in-wave histogram + stable rank via 17 ballots ----
    const int lane = tid & 63;
    const int wv   = tid >> 6;
    unsigned long long mymask = 0ull;
    #pragma unroll
    for (int k = 0; k < NB; ++k) {
        unsigned long long m = __ballot(e == k);
        if (e == k) mymask = m;
        if (lane == 0) wavecnt[wv * NB + k] = __popcll(m);
    }
    const int rank = __popcll(mymask & ((1ull << lane) - 1ull));
    __syncthreads();   // staging + wavecnt visible

    // ---- per-expert scan over waves (17 threads, 16 serial steps each) ----
    if (tid < NB) {
        int run = 0;
        #pragma unroll
        for (int w = 0; w < NW; ++w) {
            int cc = wavecnt[w * NB + tid];
            waveoff[w * NB + tid] = run;
            run += cc;
        }
        tot[tid] = run;
    }
    __syncthreads();
    if (tid == 0) {
        int run = 0;
        #pragma unroll
        for (int k = 0; k < NB; ++k) { ebase[k] = run; run += tot[k]; }
    }
    __syncthreads();

    // ---- scatter sample into expert-sorted LDS order ----
    const int slot = ebase[e] + waveoff[wv * NB + e] + rank;
    sx[slot]    = xv;
    sinfo[slot] = tid | (e << 12);
    __syncthreads();

    // ---- evaluate: waves are (almost always) expert-uniform -> LDS broadcasts ----
    const int    info = sinfo[tid];
    const float2 xs   = sx[tid];
    const int    es   = info >> 12;
    const int    oidx = info & 0xFFF;

    float result = 0.0f;
    if (es < 16) {
        const float* W = &smem[es * ESTRIDE];
        float h[HID];
        // layer 1: 2 -> 20
        {
            const float4* w0 = reinterpret_cast<const float4*>(W + OFF_W1);
            const float4* w1 = reinterpret_cast<const float4*>(W + OFF_W1 + HID);
            const float4* bb = reinterpret_cast<const float4*>(W + OFF_B1);
            #pragma unroll
            for (int q = 0; q < 5; ++q) {
                float4 a0 = w0[q], a1 = w1[q], b = bb[q];
                h[4*q+0] = silu(fmaf(xs.x, a0.x, fmaf(xs.y, a1.x, b.x)));
                h[4*q+1] = silu(fmaf(xs.x, a0.y, fmaf(xs.y, a1.y, b.y)));
                h[4*q+2] = silu(fmaf(xs.x, a0.z, fmaf(xs.y, a1.z, b.z)));
                h[4*q+3] = silu(fmaf(xs.x, a0.w, fmaf(xs.y, a1.w, b.w)));
            }
        }
        layer20(h, W + OFF_W2, W + OFF_B2);
        layer20(h, W + OFF_W3, W + OFF_B3);
        layer20(h, W + OFF_W4, W + OFF_B4);
        // layer 5: 20 -> 1
        float acc = W[OFF_B5];
        {
            const float4* w5 = reinterpret_cast<const float4*>(W + OFF_W5);
            #pragma unroll
            for (int q = 0; q < 5; ++q) {
                float4 w = w5[q];
                acc = fmaf(h[4*q+0], w.x, acc);
                acc = fmaf(h[4*q+1], w.y, acc);
                acc = fmaf(h[4*q+2], w.z, acc);
                acc = fmaf(h[4*q+3], w.w, acc);
            }
        }
        result = acc;
    }

    const int on = blockIdx.x * NTHREADS + oidx;
    if (on < n_total) out[on] = result;   // 4B scatter within block's 4KB window
}

extern "C" void kernel_launch(void* const* d_in, const int* in_sizes, int n_in,
                              void* d_out, int out_size, void* d_ws, size_t ws_size,
                              hipStream_t stream) {
    const float* x  = (const float*)d_in[0];
    const float* W1 = (const float*)d_in[1];
    const float* b1 = (const float*)d_in[2];
    const float* W2 = (const float*)d_in[3];
    const float* b2 = (const float*)d_in[4];
    const float* W3 = (const float*)d_in[5];
    const float* b3 = (const float*)d_in[6];
    const float* W4 = (const float*)d_in[7];
    const float* b4 = (const float*)d_in[8];
    const float* W5 = (const float*)d_in[9];
    const float* b5 = (const float*)d_in[10];
    float* out = (float*)d_out;

    const int n_total = in_sizes[0] / 2;                  // 262144 samples
    const int grid = (n_total + NTHREADS - 1) / NTHREADS; // 256 blocks

    hipLaunchKernelGGL(NetEval_2207613190845_kernel, dim3(grid), dim3(NTHREADS), 0, stream,
                       x, W1, b1, W2, b2, W3, b3, W4, b4, W5, b5, out, n_total);
}